// Round 1
// baseline (21602.448 us; speedup 1.0000x reference)
//
#include <hip/hip_runtime.h>
#include <hip/hip_bf16.h>
#include <math.h>

// Transformer: DEPTH=4, DIM=768, HEADS=12, HD=64, CTX=2048, B=4.
// fp32 baseline, correctness-first. x lives in d_out (B*CTX*DIM floats).
// ws usage: 4 buffers of T*DIM floats = 100.7 MB.

#define DEPTH 4
#define DIM   768
#define HEADS 12
#define HD    64
#define CTXN  2048
#define BATCH 4
#define TOKENS (BATCH * CTXN)   // 8192

// ---------------------------------------------------------------- add pos emb
__global__ __launch_bounds__(256) void add_pos_kernel(
    const float* __restrict__ X, const float* __restrict__ P,
    float* __restrict__ Y, int n, int pn) {
  int i = blockIdx.x * 256 + threadIdx.x;
  if (i < n) Y[i] = X[i] + P[i % pn];
}

// ----------------------------------------------------------------- layernorm
__global__ __launch_bounds__(256) void ln_kernel(
    const float* __restrict__ X, const float* __restrict__ g,
    const float* __restrict__ b, float* __restrict__ Y) {
  int t = blockIdx.x;
  int tid = threadIdx.x;
  const float* xr = X + (size_t)t * DIM;
  float v0 = xr[tid], v1 = xr[tid + 256], v2 = xr[tid + 512];
  float s = v0 + v1 + v2;
  float q = v0 * v0 + v1 * v1 + v2 * v2;
#pragma unroll
  for (int o = 32; o > 0; o >>= 1) {
    s += __shfl_xor(s, o);
    q += __shfl_xor(q, o);
  }
  __shared__ float rs[4], rq[4];
  int w = tid >> 6;
  if ((tid & 63) == 0) { rs[w] = s; rq[w] = q; }
  __syncthreads();
  s = rs[0] + rs[1] + rs[2] + rs[3];
  q = rq[0] + rq[1] + rq[2] + rq[3];
  float mean = s * (1.0f / DIM);
  float var  = q * (1.0f / DIM) - mean * mean;
  float r = rsqrtf(var + 1e-5f);
  float* yr = Y + (size_t)t * DIM;
  yr[tid]       = (v0 - mean) * r * g[tid]       + b[tid];
  yr[tid + 256] = (v1 - mean) * r * g[tid + 256] + b[tid + 256];
  yr[tid + 512] = (v2 - mean) * r * g[tid + 512] + b[tid + 512];
}

// ------------------------------------------------------------------ fp32 GEMM
// C[M,N] = A[M,K] @ B[K,N] (+bias) (+gelu) (+= residual into C)
// 64x64 C tile per block, 256 threads, 4x4 per thread, K-tile 16.
template <int HAS_BIAS, int HAS_GELU, int HAS_RES>
__global__ __launch_bounds__(256) void gemm_kernel(
    const float* __restrict__ A, const float* __restrict__ B,
    const float* __restrict__ bias, float* __restrict__ C,
    int M, int N, int K) {
  __shared__ float As[16][65];  // As[k][r]
  __shared__ float Bs[16][65];  // Bs[k][c]
  int tx = threadIdx.x & 15, ty = threadIdx.x >> 4;
  int row0 = blockIdx.y * 64, col0 = blockIdx.x * 64;
  float acc[4][4] = {};
  for (int kt = 0; kt < K; kt += 16) {
#pragma unroll
    for (int i = 0; i < 4; ++i) {
      int id = threadIdx.x + i * 256;
      int r = id >> 4, kk = id & 15;
      As[kk][r] = A[(size_t)(row0 + r) * K + kt + kk];
      int kk2 = id >> 6, c = id & 63;
      Bs[kk2][c] = B[(size_t)(kt + kk2) * N + col0 + c];
    }
    __syncthreads();
#pragma unroll
    for (int kk = 0; kk < 16; ++kk) {
      float a[4], bb[4];
#pragma unroll
      for (int i = 0; i < 4; ++i) a[i] = As[kk][ty + i * 16];
#pragma unroll
      for (int i = 0; i < 4; ++i) bb[i] = Bs[kk][tx + i * 16];
#pragma unroll
      for (int i = 0; i < 4; ++i)
#pragma unroll
        for (int j = 0; j < 4; ++j) acc[i][j] += a[i] * bb[j];
    }
    __syncthreads();
  }
#pragma unroll
  for (int i = 0; i < 4; ++i) {
#pragma unroll
    for (int j = 0; j < 4; ++j) {
      int r = row0 + ty + i * 16, c = col0 + tx + j * 16;
      float v = acc[i][j];
      if (HAS_BIAS) v += bias[c];
      if (HAS_GELU) v = 0.5f * v * (1.0f + erff(v * 0.70710678118654752f));
      size_t o = (size_t)r * N + c;
      if (HAS_RES) C[o] += v; else C[o] = v;
    }
  }
}

// ---------------------------------------------------------- flash attention
// One block per (batch, head, 64-row Q tile). 256 threads.
// Thread t: row r0 = t/4 of the Q tile, 16 key-cols / 16 out-dims at
// cb=(t&3)*16. Online softmax; P broadcast via __shfl (no LDS P array).
__global__ __launch_bounds__(256) void attn_kernel(
    const float* __restrict__ Q, const float* __restrict__ K,
    const float* __restrict__ V, float* __restrict__ O) {
  const int tiles = CTXN / 64;
  int bid = blockIdx.x;
  int qt = bid % tiles;
  int h  = (bid / tiles) % HEADS;
  int b  = bid / (tiles * HEADS);
  int tid = threadIdx.x;

  __shared__ float Qs[64][65];
  __shared__ float Ks[64][65];
  __shared__ float Vs[64][65];

  const float scale = 0.125f;  // 1/sqrt(64)
#pragma unroll
  for (int i = 0; i < 16; ++i) {
    int idx = i * 256 + tid;
    int r = idx >> 6, d = idx & 63;
    int t = qt * 64 + r;
    Qs[r][d] = Q[(size_t)(b * CTXN + t) * DIM + h * HD + d] * scale;
  }

  int r0 = tid >> 2;
  int cb = (tid & 3) * 16;
  int src_base = ((r0 & 15) << 2);  // first lane of my row group within wave

  float m = -1e30f, l = 0.0f;
  float o[16];
#pragma unroll
  for (int j = 0; j < 16; ++j) o[j] = 0.0f;

  for (int kt = 0; kt < tiles; ++kt) {
#pragma unroll
    for (int i = 0; i < 16; ++i) {
      int idx = i * 256 + tid;
      int c = idx >> 6, d = idx & 63;
      int t = kt * 64 + c;
      size_t gidx = (size_t)(b * CTXN + t) * DIM + h * HD + d;
      Ks[c][d] = K[gidx];
      Vs[c][d] = V[gidx];
    }
    __syncthreads();

    // scores for my row, my 16 key columns
    float s[16];
#pragma unroll
    for (int j = 0; j < 16; ++j) s[j] = 0.0f;
    for (int d = 0; d < 64; ++d) {
      float qd = Qs[r0][d];
#pragma unroll
      for (int j = 0; j < 16; ++j) s[j] += qd * Ks[cb + j][d];
    }

    // online softmax: row stats across the 4 lanes sharing this row
    float tmax = s[0];
#pragma unroll
    for (int j = 1; j < 16; ++j) tmax = fmaxf(tmax, s[j]);
    tmax = fmaxf(tmax, __shfl_xor(tmax, 1));
    tmax = fmaxf(tmax, __shfl_xor(tmax, 2));
    float mnew = fmaxf(m, tmax);
    float alpha = __expf(m - mnew);
    float ls = 0.0f;
#pragma unroll
    for (int j = 0; j < 16; ++j) {
      s[j] = __expf(s[j] - mnew);
      ls += s[j];
    }
    ls += __shfl_xor(ls, 1);
    ls += __shfl_xor(ls, 2);
    l = l * alpha + ls;
    m = mnew;
#pragma unroll
    for (int j = 0; j < 16; ++j) o[j] *= alpha;

    // P @ V: broadcast p over the 4 lanes of the row via shfl
#pragma unroll
    for (int k2 = 0; k2 < 64; ++k2) {
      float p = __shfl(s[k2 & 15], src_base | (k2 >> 4));
#pragma unroll
      for (int j = 0; j < 16; ++j) o[j] += p * Vs[k2][cb + j];
    }
    __syncthreads();
  }

  float inv = 1.0f / l;
  int t = qt * 64 + r0;
  size_t gidx = (size_t)(b * CTXN + t) * DIM + h * HD + cb;
#pragma unroll
  for (int j = 0; j < 16; ++j) O[gidx + j] = o[j] * inv;
}

// ------------------------------------------------------------------- launch
extern "C" void kernel_launch(void* const* d_in, const int* in_sizes, int n_in,
                              void* d_out, int out_size, void* d_ws, size_t ws_size,
                              hipStream_t stream) {
  const float* x_in  = (const float*)d_in[0];
  const float* pos   = (const float*)d_in[1];
  const float* ln1_g = (const float*)d_in[2];
  const float* ln1_b = (const float*)d_in[3];
  const float* Wq    = (const float*)d_in[4];
  const float* Wk    = (const float*)d_in[5];
  const float* Wv    = (const float*)d_in[6];
  const float* Wo    = (const float*)d_in[7];
  const float* ln2_g = (const float*)d_in[8];
  const float* ln2_b = (const float*)d_in[9];
  const float* W1    = (const float*)d_in[10];
  const float* b1    = (const float*)d_in[11];
  const float* W2    = (const float*)d_in[12];
  const float* b2    = (const float*)d_in[13];

  float* x = (float*)d_out;  // x lives in d_out
  const size_t TD = (size_t)TOKENS * DIM;
  float* hbuf = (float*)d_ws;
  float* qbuf = hbuf + TD;
  float* kbuf = qbuf + TD;
  float* vbuf = kbuf + TD;

  int n = (int)TD, pn = CTXN * DIM;
  add_pos_kernel<<<(n + 255) / 256, 256, 0, stream>>>(x_in, pos, x, n, pn);

  dim3 gg(DIM / 64, TOKENS / 64);  // (12, 128)
  for (int i = 0; i < DEPTH; ++i) {
    const float* wq = Wq + (size_t)i * DIM * DIM;
    const float* wk = Wk + (size_t)i * DIM * DIM;
    const float* wv = Wv + (size_t)i * DIM * DIM;
    const float* wo = Wo + (size_t)i * DIM * DIM;
    const float* w1 = W1 + (size_t)i * DIM * DIM;
    const float* w2 = W2 + (size_t)i * DIM * DIM;

    // --- attention block ---
    ln_kernel<<<TOKENS, 256, 0, stream>>>(x, ln1_g + i * DIM, ln1_b + i * DIM, hbuf);
    gemm_kernel<0,0,0><<<gg, 256, 0, stream>>>(hbuf, wq, nullptr, qbuf, TOKENS, DIM, DIM);
    gemm_kernel<0,0,0><<<gg, 256, 0, stream>>>(hbuf, wk, nullptr, kbuf, TOKENS, DIM, DIM);
    gemm_kernel<0,0,0><<<gg, 256, 0, stream>>>(hbuf, wv, nullptr, vbuf, TOKENS, DIM, DIM);
    attn_kernel<<<BATCH * HEADS * (CTXN / 64), 256, 0, stream>>>(qbuf, kbuf, vbuf, hbuf);
    gemm_kernel<0,0,1><<<gg, 256, 0, stream>>>(hbuf, wo, nullptr, x, TOKENS, DIM, DIM);

    // --- feed-forward block ---
    ln_kernel<<<TOKENS, 256, 0, stream>>>(x, ln2_g + i * DIM, ln2_b + i * DIM, hbuf);
    gemm_kernel<1,1,0><<<gg, 256, 0, stream>>>(hbuf, w1, b1 + i * DIM, qbuf, TOKENS, DIM, DIM);
    gemm_kernel<1,0,1><<<gg, 256, 0, stream>>>(qbuf, w2, b2 + i * DIM, x, TOKENS, DIM, DIM);
  }
}

// Round 4
// 4934.209 us; speedup vs baseline: 4.3781x; 4.3781x over previous
//
#include <hip/hip_runtime.h>
#include <math.h>

// Transformer: DEPTH=4, DIM=768, HEADS=12, HD=64, CTX=2048, B=4.
// R3: same flash-attention algorithm as R2, but all bf16 handled as raw
// ushort bits + short8 MFMA fragments (the guide's compile-verified form).
// GEMMs remain fp32 (QKV GEMMs emit bf16 bits for the attention path).

#define DEPTH 4
#define DIM   768
#define HEADS 12
#define HD    64
#define CTXN  2048
#define BATCH 4
#define TOKENS (BATCH * CTXN)   // 8192

typedef unsigned short u16;
typedef short s16x8 __attribute__((ext_vector_type(8)));   // 8 bf16 (4 VGPRs)
typedef float f32x4 __attribute__((ext_vector_type(4)));   // MFMA acc

// float -> bf16 bits, round-nearest-even
__device__ __forceinline__ u16 f2bf(float f) {
  union { float f; unsigned u; } c;
  c.f = f;
  unsigned u = c.u;
  return (u16)((u + 0x7FFFu + ((u >> 16) & 1u)) >> 16);
}

// ---------------------------------------------------------------- add pos emb
__global__ __launch_bounds__(256) void add_pos_kernel(
    const float* __restrict__ X, const float* __restrict__ P,
    float* __restrict__ Y, int n, int pn) {
  int i = blockIdx.x * 256 + threadIdx.x;
  if (i < n) Y[i] = X[i] + P[i % pn];
}

// ----------------------------------------------------------------- layernorm
__global__ __launch_bounds__(256) void ln_kernel(
    const float* __restrict__ X, const float* __restrict__ g,
    const float* __restrict__ b, float* __restrict__ Y) {
  int t = blockIdx.x;
  int tid = threadIdx.x;
  const float* xr = X + (size_t)t * DIM;
  float v0 = xr[tid], v1 = xr[tid + 256], v2 = xr[tid + 512];
  float s = v0 + v1 + v2;
  float q = v0 * v0 + v1 * v1 + v2 * v2;
#pragma unroll
  for (int o = 32; o > 0; o >>= 1) {
    s += __shfl_xor(s, o);
    q += __shfl_xor(q, o);
  }
  __shared__ float rs[4], rq[4];
  int w = tid >> 6;
  if ((tid & 63) == 0) { rs[w] = s; rq[w] = q; }
  __syncthreads();
  s = rs[0] + rs[1] + rs[2] + rs[3];
  q = rq[0] + rq[1] + rq[2] + rq[3];
  float mean = s * (1.0f / DIM);
  float var  = q * (1.0f / DIM) - mean * mean;
  float r = rsqrtf(var + 1e-5f);
  float* yr = Y + (size_t)t * DIM;
  yr[tid]       = (v0 - mean) * r * g[tid]       + b[tid];
  yr[tid + 256] = (v1 - mean) * r * g[tid + 256] + b[tid + 256];
  yr[tid + 512] = (v2 - mean) * r * g[tid + 512] + b[tid + 512];
}

// ------------------------------------------------------------------ fp32 GEMM
// C[M,N] = A[M,K] @ B[K,N] (+bias) (+gelu) (+= residual) (optionally bf16 out)
template <int HAS_BIAS, int HAS_GELU, int HAS_RES, int OUT_BF16>
__global__ __launch_bounds__(256) void gemm_kernel(
    const float* __restrict__ A, const float* __restrict__ B,
    const float* __restrict__ bias, void* __restrict__ Cv,
    int M, int N, int K) {
  float* C = (float*)Cv;
  u16* Cb = (u16*)Cv;
  __shared__ float As[16][65];
  __shared__ float Bs[16][65];
  int tx = threadIdx.x & 15, ty = threadIdx.x >> 4;
  int row0 = blockIdx.y * 64, col0 = blockIdx.x * 64;
  float acc[4][4] = {};
  for (int kt = 0; kt < K; kt += 16) {
#pragma unroll
    for (int i = 0; i < 4; ++i) {
      int id = threadIdx.x + i * 256;
      int r = id >> 4, kk = id & 15;
      As[kk][r] = A[(size_t)(row0 + r) * K + kt + kk];
      int kk2 = id >> 6, c = id & 63;
      Bs[kk2][c] = B[(size_t)(kt + kk2) * N + col0 + c];
    }
    __syncthreads();
#pragma unroll
    for (int kk = 0; kk < 16; ++kk) {
      float a[4], bb[4];
#pragma unroll
      for (int i = 0; i < 4; ++i) a[i] = As[kk][ty + i * 16];
#pragma unroll
      for (int i = 0; i < 4; ++i) bb[i] = Bs[kk][tx + i * 16];
#pragma unroll
      for (int i = 0; i < 4; ++i)
#pragma unroll
        for (int j = 0; j < 4; ++j) acc[i][j] += a[i] * bb[j];
    }
    __syncthreads();
  }
#pragma unroll
  for (int i = 0; i < 4; ++i) {
#pragma unroll
    for (int j = 0; j < 4; ++j) {
      int r = row0 + ty + i * 16, c = col0 + tx + j * 16;
      float v = acc[i][j];
      if (HAS_BIAS) v += bias[c];
      if (HAS_GELU) v = 0.5f * v * (1.0f + erff(v * 0.70710678118654752f));
      size_t o = (size_t)r * N + c;
      if (OUT_BF16) { Cb[o] = f2bf(v); }
      else if (HAS_RES) { C[o] += v; }
      else { C[o] = v; }
    }
  }
}

// ------------------------------- V transpose: [T][768] -> [b][h][64][2048]
__global__ __launch_bounds__(256) void vtrans_kernel(
    const u16* __restrict__ Vb, u16* __restrict__ Vt) {
  int bid = blockIdx.x;
  int tt = bid & 31;
  int h  = (bid >> 5) % HEADS;
  int b  = bid / (32 * HEADS);
  int tid = threadIdx.x;
  __shared__ u16 T[64][66];
  const u16* src = Vb + ((size_t)(b * CTXN + tt * 64)) * DIM + h * HD;
#pragma unroll
  for (int i = 0; i < 2; ++i) {
    int idx = tid + i * 256, r = idx >> 3, g = idx & 7;
    s16x8 v = *(const s16x8*)&src[(size_t)r * DIM + g * 8];
#pragma unroll
    for (int j = 0; j < 8; ++j) T[g * 8 + j][r] = (u16)v[j];
  }
  __syncthreads();
#pragma unroll
  for (int i = 0; i < 2; ++i) {
    int idx = tid + i * 256, d = idx >> 3, g = idx & 7;
    s16x8 w;
#pragma unroll
    for (int j = 0; j < 8; ++j) w[j] = (short)T[d][g * 8 + j];
    *(s16x8*)&Vt[((size_t)(b * HEADS + h) * HD + d) * CTXN + tt * 64 + g * 8] = w;
  }
}

// -------------------------------------------------- bf16 MFMA flash attention
// LDS tiles are 64x64 bf16 stored as 8-elem groups XOR-swizzled by (row&7) so
// fragment reads/writes are 16B and bank-balanced.
__device__ __forceinline__ s16x8 ldfrag(const u16* t, int r, int g) {
  return *(const s16x8*)(t + r * 64 + 8 * (g ^ (r & 7)));
}
__device__ __forceinline__ void stfrag(u16* t, int r, int g, s16x8 v) {
  *(s16x8*)(t + r * 64 + 8 * (g ^ (r & 7))) = v;
}

__global__ __launch_bounds__(256) void attn_kernel(
    const u16* __restrict__ Qb, const u16* __restrict__ Kb,
    const u16* __restrict__ Vt, float* __restrict__ O) {
  const int tiles = CTXN / 64;
  int bid = blockIdx.x;
  int qt = bid % tiles;
  int h  = (bid / tiles) % HEADS;
  int b  = bid / (tiles * HEADS);
  int tid = threadIdx.x;
  int wave = tid >> 6, lane = tid & 63, ln = lane & 15, quad = lane >> 4;

  // LDS pool, 17152 B total. Of aliases Ks+Ps (only live after the K-loop).
  __shared__ __align__(16) char smem[17152];
  float* lsum   = (float*)smem;             // [64]   256 B
  float* alphas = (float*)(smem + 256);     // [64]   256 B
  u16* Ks       = (u16*)(smem + 512);       // 64x64  8192 B
  u16* Ps       = (u16*)(smem + 8704);      // 64x64  8192 B
  float (*Of)[65] = (float (*)[65])(smem + 512);  // 64x65 fp32, 16640 B

  // loop-invariant Q fragments, direct from global (no intra-block reuse)
  const u16* qrow =
      Qb + ((size_t)(b * CTXN + qt * 64 + wave * 16 + ln)) * DIM + h * HD;
  s16x8 aq0 = *(const s16x8*)&qrow[quad * 8];
  s16x8 aq1 = *(const s16x8*)&qrow[32 + quad * 8];

  float m_r[4], l_r[4];
  f32x4 oacc[4];
  const f32x4 zero = {0.0f, 0.0f, 0.0f, 0.0f};
#pragma unroll
  for (int i = 0; i < 4; ++i) { m_r[i] = -1e30f; l_r[i] = 0.0f; oacc[i] = zero; }

  const u16* kb0 = Kb + ((size_t)b * CTXN) * DIM + h * HD;
  const u16* vrow =
      Vt + ((size_t)(b * HEADS + h) * HD + wave * 16 + ln) * CTXN;

  for (int kt = 0; kt < tiles; ++kt) {
    // stage K tile [c][d] into LDS (4x reuse across waves)
#pragma unroll
    for (int i = 0; i < 2; ++i) {
      int idx = tid + i * 256, r = idx >> 3, g = idx & 7;
      stfrag(Ks, r, g, *(const s16x8*)&kb0[(size_t)(kt * 64 + r) * DIM + g * 8]);
    }
    // V^T fragments direct from global (each element used exactly once)
    s16x8 av0 = *(const s16x8*)&vrow[kt * 64 + quad * 8];
    s16x8 av1 = *(const s16x8*)&vrow[kt * 64 + 32 + quad * 8];
    __syncthreads();

    // S strip (16 q-rows x 64 k-cols per wave) = Q A-frag x K B-frag
    f32x4 sacc[4];
#pragma unroll
    for (int nb = 0; nb < 4; ++nb) {
      sacc[nb] = zero;
      s16x8 b0 = ldfrag(Ks, nb * 16 + ln, quad);
      s16x8 b1 = ldfrag(Ks, nb * 16 + ln, 4 + quad);
      sacc[nb] = __builtin_amdgcn_mfma_f32_16x16x32_bf16(aq0, b0, sacc[nb], 0, 0, 0);
      sacc[nb] = __builtin_amdgcn_mfma_f32_16x16x32_bf16(aq1, b1, sacc[nb], 0, 0, 0);
    }

    // online softmax; D layout: row=quad*4+reg, col=nb*16+ln
#pragma unroll
    for (int reg = 0; reg < 4; ++reg) {
      int r = wave * 16 + quad * 4 + reg;
      float s0 = sacc[0][reg] * 0.125f, s1 = sacc[1][reg] * 0.125f;
      float s2 = sacc[2][reg] * 0.125f, s3 = sacc[3][reg] * 0.125f;
      float mx = fmaxf(fmaxf(s0, s1), fmaxf(s2, s3));
      mx = fmaxf(mx, __shfl_xor(mx, 1));
      mx = fmaxf(mx, __shfl_xor(mx, 2));
      mx = fmaxf(mx, __shfl_xor(mx, 4));
      mx = fmaxf(mx, __shfl_xor(mx, 8));
      float mnew = fmaxf(m_r[reg], mx);
      float a = __expf(m_r[reg] - mnew);
      float p0 = __expf(s0 - mnew), p1 = __expf(s1 - mnew);
      float p2 = __expf(s2 - mnew), p3 = __expf(s3 - mnew);
      float ls = p0 + p1 + p2 + p3;
      ls += __shfl_xor(ls, 1);
      ls += __shfl_xor(ls, 2);
      ls += __shfl_xor(ls, 4);
      ls += __shfl_xor(ls, 8);
      l_r[reg] = l_r[reg] * a + ls;
      m_r[reg] = mnew;
      int rs = r & 7;
      int base = r * 64 + (ln & 7);
      int gq = ln >> 3;
      Ps[base + 8 * ((0 + gq) ^ rs)] = f2bf(p0);
      Ps[base + 8 * ((2 + gq) ^ rs)] = f2bf(p1);
      Ps[base + 8 * ((4 + gq) ^ rs)] = f2bf(p2);
      Ps[base + 8 * ((6 + gq) ^ rs)] = f2bf(p3);
      if (ln == 0) alphas[r] = a;
    }
    __syncthreads();

    // O^T strip (16 d-rows x 64 q-cols per wave) += V^T A-frag x P B-frag
#pragma unroll
    for (int nb = 0; nb < 4; ++nb) {
      float al = alphas[nb * 16 + ln];
      oacc[nb][0] *= al; oacc[nb][1] *= al;
      oacc[nb][2] *= al; oacc[nb][3] *= al;
      s16x8 p0 = ldfrag(Ps, nb * 16 + ln, quad);
      s16x8 p1 = ldfrag(Ps, nb * 16 + ln, 4 + quad);
      oacc[nb] = __builtin_amdgcn_mfma_f32_16x16x32_bf16(av0, p0, oacc[nb], 0, 0, 0);
      oacc[nb] = __builtin_amdgcn_mfma_f32_16x16x32_bf16(av1, p1, oacc[nb], 0, 0, 0);
    }
    __syncthreads();
  }

  // final: normalize by 1/l and write out (transpose via LDS for coalescing)
  if (ln == 0) {
#pragma unroll
    for (int reg = 0; reg < 4; ++reg) lsum[wave * 16 + quad * 4 + reg] = l_r[reg];
  }
  __syncthreads();
#pragma unroll
  for (int nb = 0; nb < 4; ++nb) {
    float linv = 1.0f / lsum[nb * 16 + ln];
#pragma unroll
    for (int reg = 0; reg < 4; ++reg)
      Of[nb * 16 + ln][wave * 16 + quad * 4 + reg] = oacc[nb][reg] * linv;
  }
  __syncthreads();
  {
    int r = tid >> 2, c0 = (tid & 3) * 16;
    float* dst = O + ((size_t)(b * CTXN + qt * 64 + r)) * DIM + h * HD + c0;
#pragma unroll
    for (int k = 0; k < 4; ++k) {
      float4 f = make_float4(Of[r][c0 + 4 * k], Of[r][c0 + 4 * k + 1],
                             Of[r][c0 + 4 * k + 2], Of[r][c0 + 4 * k + 3]);
      *(float4*)&dst[4 * k] = f;
    }
  }
}

// ------------------------------------------------------------------- launch
extern "C" void kernel_launch(void* const* d_in, const int* in_sizes, int n_in,
                              void* d_out, int out_size, void* d_ws, size_t ws_size,
                              hipStream_t stream) {
  const float* x_in  = (const float*)d_in[0];
  const float* pos   = (const float*)d_in[1];
  const float* ln1_g = (const float*)d_in[2];
  const float* ln1_b = (const float*)d_in[3];
  const float* Wq    = (const float*)d_in[4];
  const float* Wk    = (const float*)d_in[5];
  const float* Wv    = (const float*)d_in[6];
  const float* Wo    = (const float*)d_in[7];
  const float* ln2_g = (const float*)d_in[8];
  const float* ln2_b = (const float*)d_in[9];
  const float* W1    = (const float*)d_in[10];
  const float* b1    = (const float*)d_in[11];
  const float* W2    = (const float*)d_in[12];
  const float* b2    = (const float*)d_in[13];

  float* x = (float*)d_out;
  const size_t TD = (size_t)TOKENS * DIM;
  float* hbuf = (float*)d_ws;        // fp32 TD
  float* fbuf = hbuf + TD;           // fp32 TD
  u16* qb = (u16*)(fbuf + TD);       // bf16 bits, TD each
  u16* kb = qb + TD;
  u16* vb = kb + TD;
  u16* vt = vb + TD;                 // V^T [b][h][64][2048]

  int n = (int)TD, pn = CTXN * DIM;
  add_pos_kernel<<<(n + 255) / 256, 256, 0, stream>>>(x_in, pos, x, n, pn);

  dim3 gg(DIM / 64, TOKENS / 64);  // (12, 128)
  int nblk_attn = BATCH * HEADS * (CTXN / 64);  // 1536
  for (int i = 0; i < DEPTH; ++i) {
    const float* wq = Wq + (size_t)i * DIM * DIM;
    const float* wk = Wk + (size_t)i * DIM * DIM;
    const float* wv = Wv + (size_t)i * DIM * DIM;
    const float* wo = Wo + (size_t)i * DIM * DIM;
    const float* w1 = W1 + (size_t)i * DIM * DIM;
    const float* w2 = W2 + (size_t)i * DIM * DIM;

    // --- attention block ---
    ln_kernel<<<TOKENS, 256, 0, stream>>>(x, ln1_g + i * DIM, ln1_b + i * DIM, hbuf);
    gemm_kernel<0,0,0,1><<<gg, 256, 0, stream>>>(hbuf, wq, nullptr, qb, TOKENS, DIM, DIM);
    gemm_kernel<0,0,0,1><<<gg, 256, 0, stream>>>(hbuf, wk, nullptr, kb, TOKENS, DIM, DIM);
    gemm_kernel<0,0,0,1><<<gg, 256, 0, stream>>>(hbuf, wv, nullptr, vb, TOKENS, DIM, DIM);
    vtrans_kernel<<<nblk_attn, 256, 0, stream>>>(vb, vt);
    attn_kernel<<<nblk_attn, 256, 0, stream>>>(qb, kb, vt, hbuf);
    gemm_kernel<0,0,1,0><<<gg, 256, 0, stream>>>(hbuf, wo, nullptr, x, TOKENS, DIM, DIM);

    // --- feed-forward block ---
    ln_kernel<<<TOKENS, 256, 0, stream>>>(x, ln2_g + i * DIM, ln2_b + i * DIM, hbuf);
    gemm_kernel<1,1,0,0><<<gg, 256, 0, stream>>>(hbuf, w1, b1 + i * DIM, fbuf, TOKENS, DIM, DIM);
    gemm_kernel<1,0,1,0><<<gg, 256, 0, stream>>>(fbuf, w2, b2 + i * DIM, x, TOKENS, DIM, DIM);
  }
}

// Round 5
// 2018.295 us; speedup vs baseline: 10.7033x; 2.4447x over previous
//
#include <hip/hip_runtime.h>
#include <math.h>

// Transformer: DEPTH=4, DIM=768, HEADS=12, HD=64, CTX=2048, B=4.
// R4: all GEMMs -> bf16 MFMA (128x128 tile, BK=64, XOR-swizzled LDS frags,
// B^T weight layout built by a per-launch fp32->bf16 transpose kernel).
// LN and attention emit bf16 activations; residuals stay fp32.

#define DEPTH 4
#define DIM   768
#define HEADS 12
#define HD    64
#define CTXN  2048
#define BATCH 4
#define TOKENS (BATCH * CTXN)   // 8192

typedef unsigned short u16;
typedef short s16x8 __attribute__((ext_vector_type(8)));   // 8 bf16 (4 VGPRs)
typedef float f32x4 __attribute__((ext_vector_type(4)));   // MFMA acc
typedef u16  u16x4 __attribute__((ext_vector_type(4)));

// float -> bf16 bits, round-nearest-even
__device__ __forceinline__ u16 f2bf(float f) {
  union { float f; unsigned u; } c;
  c.f = f;
  unsigned u = c.u;
  return (u16)((u + 0x7FFFu + ((u >> 16) & 1u)) >> 16);
}

// 64-elem-row bf16 tile helpers: 8-elem groups XOR-swizzled by (row&7),
// 16B aligned accesses, 2-way bank aliasing (free).
__device__ __forceinline__ s16x8 ldfrag(const u16* t, int r, int g) {
  return *(const s16x8*)(t + r * 64 + 8 * (g ^ (r & 7)));
}
__device__ __forceinline__ void stfrag(u16* t, int r, int g, s16x8 v) {
  *(s16x8*)(t + r * 64 + 8 * (g ^ (r & 7))) = v;
}

// ---------------------------------------------------------------- add pos emb
__global__ __launch_bounds__(256) void add_pos_kernel(
    const float* __restrict__ X, const float* __restrict__ P,
    float* __restrict__ Y, int n, int pn) {
  int i = blockIdx.x * 256 + threadIdx.x;
  if (i < n) Y[i] = X[i] + P[i % pn];
}

// ------------------------------------------- weight fp32 -> bf16 + transpose
// src W[k][n] (768x768 fp32) -> dst Wt[n][k] (768x768 bf16 bits)
__global__ __launch_bounds__(256) void wconv_kernel(
    const float* __restrict__ Wq, const float* __restrict__ Wk,
    const float* __restrict__ Wv, const float* __restrict__ Wo,
    const float* __restrict__ W1, const float* __restrict__ W2,
    u16* __restrict__ dst) {
  int mat = blockIdx.z;             // 0..23 = layer*6 + type
  int layer = mat / 6, type = mat % 6;
  const float* srcs[6] = {Wq, Wk, Wv, Wo, W1, W2};
  const float* src = srcs[type] + (size_t)layer * DIM * DIM;
  u16* d = dst + (size_t)mat * DIM * DIM;
  __shared__ float L[32][33];
  int k0 = blockIdx.y * 32, n0 = blockIdx.x * 32;
  int r = threadIdx.x >> 3, c4 = (threadIdx.x & 7) * 4;
  float4 v = *(const float4*)&src[(size_t)(k0 + r) * DIM + n0 + c4];
  L[c4 + 0][r] = v.x; L[c4 + 1][r] = v.y;
  L[c4 + 2][r] = v.z; L[c4 + 3][r] = v.w;
  __syncthreads();
  u16x4 w;
#pragma unroll
  for (int j = 0; j < 4; ++j) w[j] = f2bf(L[r][c4 + j]);
  *(u16x4*)&d[(size_t)(n0 + r) * DIM + k0 + c4] = w;
}

// ----------------------------------------------------- layernorm (bf16 out)
__global__ __launch_bounds__(256) void ln_kernel(
    const float* __restrict__ X, const float* __restrict__ g,
    const float* __restrict__ b, u16* __restrict__ Y) {
  int t = blockIdx.x;
  int tid = threadIdx.x;
  const float* xr = X + (size_t)t * DIM;
  float v0 = xr[tid], v1 = xr[tid + 256], v2 = xr[tid + 512];
  float s = v0 + v1 + v2;
  float q = v0 * v0 + v1 * v1 + v2 * v2;
#pragma unroll
  for (int o = 32; o > 0; o >>= 1) {
    s += __shfl_xor(s, o);
    q += __shfl_xor(q, o);
  }
  __shared__ float rs[4], rq[4];
  int w = tid >> 6;
  if ((tid & 63) == 0) { rs[w] = s; rq[w] = q; }
  __syncthreads();
  s = rs[0] + rs[1] + rs[2] + rs[3];
  q = rq[0] + rq[1] + rq[2] + rq[3];
  float mean = s * (1.0f / DIM);
  float var  = q * (1.0f / DIM) - mean * mean;
  float r = rsqrtf(var + 1e-5f);
  u16* yr = Y + (size_t)t * DIM;
  yr[tid]       = f2bf((v0 - mean) * r * g[tid]       + b[tid]);
  yr[tid + 256] = f2bf((v1 - mean) * r * g[tid + 256] + b[tid + 256]);
  yr[tid + 512] = f2bf((v2 - mean) * r * g[tid + 512] + b[tid + 512]);
}

// ------------------------------------------------------------ bf16 MFMA GEMM
// C[M=8192][N=768] = A[M][768] @ Bt[N=768][K=768]^T  (A, Bt bf16 row-major)
// 128x128 tile, 4 waves (64x64 each), BK=64.
template <int HAS_BIAS, int HAS_GELU, int HAS_RES, int OUT_BF16>
__global__ __launch_bounds__(256, 3) void gemm_bf16(
    const u16* __restrict__ A, const u16* __restrict__ Bt,
    const float* __restrict__ bias, void* __restrict__ Cv) {
  float* C = (float*)Cv;
  u16* Cb = (u16*)Cv;
  __shared__ __align__(16) u16 As[128 * 64];
  __shared__ __align__(16) u16 Bs[128 * 64];
  int tid = threadIdx.x;
  int wave = tid >> 6, lane = tid & 63, ln = lane & 15, quad = lane >> 4;
  int wr = wave >> 1, wc = wave & 1;
  int m0 = blockIdx.y * 128, n0 = blockIdx.x * 128;

  f32x4 acc[4][4];
  const f32x4 zero = {0.0f, 0.0f, 0.0f, 0.0f};
#pragma unroll
  for (int i = 0; i < 4; ++i)
#pragma unroll
    for (int j = 0; j < 4; ++j) acc[i][j] = zero;

  for (int kt = 0; kt < DIM / 64; ++kt) {
#pragma unroll
    for (int i = 0; i < 4; ++i) {
      int s = tid + i * 256;          // 0..1023
      int r = s >> 3, g = s & 7;
      stfrag(As, r, g, *(const s16x8*)&A[(size_t)(m0 + r) * DIM + kt * 64 + g * 8]);
      stfrag(Bs, r, g, *(const s16x8*)&Bt[(size_t)(n0 + r) * DIM + kt * 64 + g * 8]);
    }
    __syncthreads();

    s16x8 bfr0[4], bfr1[4];
#pragma unroll
    for (int ni = 0; ni < 4; ++ni) {
      bfr0[ni] = ldfrag(Bs, wc * 64 + ni * 16 + ln, quad);
      bfr1[ni] = ldfrag(Bs, wc * 64 + ni * 16 + ln, 4 + quad);
    }
#pragma unroll
    for (int mi = 0; mi < 4; ++mi) {
      s16x8 a0 = ldfrag(As, wr * 64 + mi * 16 + ln, quad);
      s16x8 a1 = ldfrag(As, wr * 64 + mi * 16 + ln, 4 + quad);
#pragma unroll
      for (int ni = 0; ni < 4; ++ni) {
        acc[mi][ni] = __builtin_amdgcn_mfma_f32_16x16x32_bf16(a0, bfr0[ni], acc[mi][ni], 0, 0, 0);
        acc[mi][ni] = __builtin_amdgcn_mfma_f32_16x16x32_bf16(a1, bfr1[ni], acc[mi][ni], 0, 0, 0);
      }
    }
    __syncthreads();
  }

  // epilogue: C/D layout col=ln, row=quad*4+reg
#pragma unroll
  for (int ni = 0; ni < 4; ++ni) {
    int c = n0 + wc * 64 + ni * 16 + ln;
    float bv = HAS_BIAS ? bias[c] : 0.0f;
#pragma unroll
    for (int mi = 0; mi < 4; ++mi) {
#pragma unroll
      for (int reg = 0; reg < 4; ++reg) {
        int r = m0 + wr * 64 + mi * 16 + quad * 4 + reg;
        float v = acc[mi][ni][reg] + bv;
        if (HAS_GELU) v = 0.5f * v * (1.0f + erff(v * 0.70710678118654752f));
        size_t o = (size_t)r * DIM + c;
        if (OUT_BF16) { Cb[o] = f2bf(v); }
        else if (HAS_RES) { C[o] += v; }
        else { C[o] = v; }
      }
    }
  }
}

// ------------------------------- V transpose: [T][768] -> [b][h][64][2048]
__global__ __launch_bounds__(256) void vtrans_kernel(
    const u16* __restrict__ Vb, u16* __restrict__ Vt) {
  int bid = blockIdx.x;
  int tt = bid & 31;
  int h  = (bid >> 5) % HEADS;
  int b  = bid / (32 * HEADS);
  int tid = threadIdx.x;
  __shared__ u16 T[64][66];
  const u16* src = Vb + ((size_t)(b * CTXN + tt * 64)) * DIM + h * HD;
#pragma unroll
  for (int i = 0; i < 2; ++i) {
    int idx = tid + i * 256, r = idx >> 3, g = idx & 7;
    s16x8 v = *(const s16x8*)&src[(size_t)r * DIM + g * 8];
#pragma unroll
    for (int j = 0; j < 8; ++j) T[g * 8 + j][r] = (u16)v[j];
  }
  __syncthreads();
#pragma unroll
  for (int i = 0; i < 2; ++i) {
    int idx = tid + i * 256, d = idx >> 3, g = idx & 7;
    s16x8 w;
#pragma unroll
    for (int j = 0; j < 8; ++j) w[j] = (short)T[d][g * 8 + j];
    *(s16x8*)&Vt[((size_t)(b * HEADS + h) * HD + d) * CTXN + tt * 64 + g * 8] = w;
  }
}

// -------------------------------------------------- bf16 MFMA flash attention
__global__ __launch_bounds__(256) void attn_kernel(
    const u16* __restrict__ Qb, const u16* __restrict__ Kb,
    const u16* __restrict__ Vt, u16* __restrict__ Ob) {
  const int tiles = CTXN / 64;
  int bid = blockIdx.x;
  int qt = bid % tiles;
  int h  = (bid / tiles) % HEADS;
  int b  = bid / (tiles * HEADS);
  int tid = threadIdx.x;
  int wave = tid >> 6, lane = tid & 63, ln = lane & 15, quad = lane >> 4;

  // LDS pool, 17152 B. Of aliases Ks+Ps (only live after the K-loop).
  __shared__ __align__(16) char smem[17152];
  float* lsum   = (float*)smem;             // [64]
  float* alphas = (float*)(smem + 256);     // [64]
  u16* Ks       = (u16*)(smem + 512);       // 64x64
  u16* Ps       = (u16*)(smem + 8704);      // 64x64
  float (*Of)[65] = (float (*)[65])(smem + 512);  // 64x65 fp32

  const u16* qrow =
      Qb + ((size_t)(b * CTXN + qt * 64 + wave * 16 + ln)) * DIM + h * HD;
  s16x8 aq0 = *(const s16x8*)&qrow[quad * 8];
  s16x8 aq1 = *(const s16x8*)&qrow[32 + quad * 8];

  float m_r[4], l_r[4];
  f32x4 oacc[4];
  const f32x4 zero = {0.0f, 0.0f, 0.0f, 0.0f};
#pragma unroll
  for (int i = 0; i < 4; ++i) { m_r[i] = -1e30f; l_r[i] = 0.0f; oacc[i] = zero; }

  const u16* kb0 = Kb + ((size_t)b * CTXN) * DIM + h * HD;
  const u16* vrow =
      Vt + ((size_t)(b * HEADS + h) * HD + wave * 16 + ln) * CTXN;

  for (int kt = 0; kt < tiles; ++kt) {
#pragma unroll
    for (int i = 0; i < 2; ++i) {
      int idx = tid + i * 256, r = idx >> 3, g = idx & 7;
      stfrag(Ks, r, g, *(const s16x8*)&kb0[(size_t)(kt * 64 + r) * DIM + g * 8]);
    }
    s16x8 av0 = *(const s16x8*)&vrow[kt * 64 + quad * 8];
    s16x8 av1 = *(const s16x8*)&vrow[kt * 64 + 32 + quad * 8];
    __syncthreads();

    f32x4 sacc[4];
#pragma unroll
    for (int nb = 0; nb < 4; ++nb) {
      sacc[nb] = zero;
      s16x8 b0 = ldfrag(Ks, nb * 16 + ln, quad);
      s16x8 b1 = ldfrag(Ks, nb * 16 + ln, 4 + quad);
      sacc[nb] = __builtin_amdgcn_mfma_f32_16x16x32_bf16(aq0, b0, sacc[nb], 0, 0, 0);
      sacc[nb] = __builtin_amdgcn_mfma_f32_16x16x32_bf16(aq1, b1, sacc[nb], 0, 0, 0);
    }

#pragma unroll
    for (int reg = 0; reg < 4; ++reg) {
      int r = wave * 16 + quad * 4 + reg;
      float s0 = sacc[0][reg] * 0.125f, s1 = sacc[1][reg] * 0.125f;
      float s2 = sacc[2][reg] * 0.125f, s3 = sacc[3][reg] * 0.125f;
      float mx = fmaxf(fmaxf(s0, s1), fmaxf(s2, s3));
      mx = fmaxf(mx, __shfl_xor(mx, 1));
      mx = fmaxf(mx, __shfl_xor(mx, 2));
      mx = fmaxf(mx, __shfl_xor(mx, 4));
      mx = fmaxf(mx, __shfl_xor(mx, 8));
      float mnew = fmaxf(m_r[reg], mx);
      float a = __expf(m_r[reg] - mnew);
      float p0 = __expf(s0 - mnew), p1 = __expf(s1 - mnew);
      float p2 = __expf(s2 - mnew), p3 = __expf(s3 - mnew);
      float ls = p0 + p1 + p2 + p3;
      ls += __shfl_xor(ls, 1);
      ls += __shfl_xor(ls, 2);
      ls += __shfl_xor(ls, 4);
      ls += __shfl_xor(ls, 8);
      l_r[reg] = l_r[reg] * a + ls;
      m_r[reg] = mnew;
      int rs = r & 7;
      int base = r * 64 + (ln & 7);
      int gq = ln >> 3;
      Ps[base + 8 * ((0 + gq) ^ rs)] = f2bf(p0);
      Ps[base + 8 * ((2 + gq) ^ rs)] = f2bf(p1);
      Ps[base + 8 * ((4 + gq) ^ rs)] = f2bf(p2);
      Ps[base + 8 * ((6 + gq) ^ rs)] = f2bf(p3);
      if (ln == 0) alphas[r] = a;
    }
    __syncthreads();

#pragma unroll
    for (int nb = 0; nb < 4; ++nb) {
      float al = alphas[nb * 16 + ln];
      oacc[nb][0] *= al; oacc[nb][1] *= al;
      oacc[nb][2] *= al; oacc[nb][3] *= al;
      s16x8 p0 = ldfrag(Ps, nb * 16 + ln, quad);
      s16x8 p1 = ldfrag(Ps, nb * 16 + ln, 4 + quad);
      oacc[nb] = __builtin_amdgcn_mfma_f32_16x16x32_bf16(av0, p0, oacc[nb], 0, 0, 0);
      oacc[nb] = __builtin_amdgcn_mfma_f32_16x16x32_bf16(av1, p1, oacc[nb], 0, 0, 0);
    }
    __syncthreads();
  }

  if (ln == 0) {
#pragma unroll
    for (int reg = 0; reg < 4; ++reg) lsum[wave * 16 + quad * 4 + reg] = l_r[reg];
  }
  __syncthreads();
#pragma unroll
  for (int nb = 0; nb < 4; ++nb) {
    float linv = 1.0f / lsum[nb * 16 + ln];
#pragma unroll
    for (int reg = 0; reg < 4; ++reg)
      Of[nb * 16 + ln][wave * 16 + quad * 4 + reg] = oacc[nb][reg] * linv;
  }
  __syncthreads();
  {
    int r = tid >> 2, c0 = (tid & 3) * 16;
    u16* dst = Ob + ((size_t)(b * CTXN + qt * 64 + r)) * DIM + h * HD + c0;
#pragma unroll
    for (int k = 0; k < 4; ++k) {
      u16x4 w;
#pragma unroll
      for (int j = 0; j < 4; ++j) w[j] = f2bf(Of[r][c0 + 4 * k + j]);
      *(u16x4*)&dst[4 * k] = w;
    }
  }
}

// ------------------------------------------------------------------- launch
extern "C" void kernel_launch(void* const* d_in, const int* in_sizes, int n_in,
                              void* d_out, int out_size, void* d_ws, size_t ws_size,
                              hipStream_t stream) {
  const float* x_in  = (const float*)d_in[0];
  const float* pos   = (const float*)d_in[1];
  const float* ln1_g = (const float*)d_in[2];
  const float* ln1_b = (const float*)d_in[3];
  const float* Wq    = (const float*)d_in[4];
  const float* Wk    = (const float*)d_in[5];
  const float* Wv    = (const float*)d_in[6];
  const float* Wo    = (const float*)d_in[7];
  const float* ln2_g = (const float*)d_in[8];
  const float* ln2_b = (const float*)d_in[9];
  const float* W1    = (const float*)d_in[10];
  const float* b1    = (const float*)d_in[11];
  const float* W2    = (const float*)d_in[12];
  const float* b2    = (const float*)d_in[13];

  float* x = (float*)d_out;
  const size_t TD = (size_t)TOKENS * DIM;
  // ws layout (u16): hb | qb | kb | vb(=fb) | vt | weights(24*768*768)
  u16* hb = (u16*)d_ws;
  u16* qb = hb + TD;
  u16* kb = qb + TD;
  u16* vb = kb + TD;   // aliased as fb for the FFN
  u16* vt = vb + TD;
  u16* wt = vt + TD;
  u16* fb = vb;

  int n = (int)TD, pn = CTXN * DIM;
  add_pos_kernel<<<(n + 255) / 256, 256, 0, stream>>>(x_in, pos, x, n, pn);
  {
    dim3 wg(24, 24, 24);
    wconv_kernel<<<wg, 256, 0, stream>>>(Wq, Wk, Wv, Wo, W1, W2, wt);
  }

  const size_t WSZ = (size_t)DIM * DIM;
  dim3 gg(DIM / 128, TOKENS / 128);  // (6, 64)
  int nblk_attn = BATCH * HEADS * (CTXN / 64);  // 1536
  for (int i = 0; i < DEPTH; ++i) {
    const u16* wq = wt + (size_t)(i * 6 + 0) * WSZ;
    const u16* wk = wt + (size_t)(i * 6 + 1) * WSZ;
    const u16* wv = wt + (size_t)(i * 6 + 2) * WSZ;
    const u16* wo = wt + (size_t)(i * 6 + 3) * WSZ;
    const u16* w1 = wt + (size_t)(i * 6 + 4) * WSZ;
    const u16* w2 = wt + (size_t)(i * 6 + 5) * WSZ;

    // --- attention block ---
    ln_kernel<<<TOKENS, 256, 0, stream>>>(x, ln1_g + i * DIM, ln1_b + i * DIM, hb);
    gemm_bf16<0,0,0,1><<<gg, 256, 0, stream>>>(hb, wq, nullptr, qb);
    gemm_bf16<0,0,0,1><<<gg, 256, 0, stream>>>(hb, wk, nullptr, kb);
    gemm_bf16<0,0,0,1><<<gg, 256, 0, stream>>>(hb, wv, nullptr, vb);
    vtrans_kernel<<<nblk_attn, 256, 0, stream>>>(vb, vt);
    attn_kernel<<<nblk_attn, 256, 0, stream>>>(qb, kb, vt, hb);
    gemm_bf16<0,0,1,0><<<gg, 256, 0, stream>>>(hb, wo, nullptr, x);

    // --- feed-forward block ---
    ln_kernel<<<TOKENS, 256, 0, stream>>>(x, ln2_g + i * DIM, ln2_b + i * DIM, hb);
    gemm_bf16<1,1,0,1><<<gg, 256, 0, stream>>>(hb, w1, b1 + i * DIM, fb);
    gemm_bf16<1,0,1,0><<<gg, 256, 0, stream>>>(fb, w2, b2 + i * DIM, x);
  }
}

// Round 6
// 1824.234 us; speedup vs baseline: 11.8419x; 1.1064x over previous
//
#include <hip/hip_runtime.h>
#include <math.h>

// Transformer: DEPTH=4, DIM=768, HEADS=12, HD=64, CTX=2048, B=4.
// R5: attention restructured to compute S^T (swap MFMA operands) so softmax
// state is per-lane scalar, P-writes are 8B-contiguous, and reductions are
// 2 shuffles. exp2-domain softmax. V^T staged in LDS. GEMMs unchanged.

#define DEPTH 4
#define DIM   768
#define HEADS 12
#define HD    64
#define CTXN  2048
#define BATCH 4
#define TOKENS (BATCH * CTXN)   // 8192

typedef unsigned short u16;
typedef short s16x8 __attribute__((ext_vector_type(8)));   // 8 bf16 (4 VGPRs)
typedef float f32x4 __attribute__((ext_vector_type(4)));   // MFMA acc
typedef u16  u16x4 __attribute__((ext_vector_type(4)));

// float -> bf16 bits, round-nearest-even
__device__ __forceinline__ u16 f2bf(float f) {
  union { float f; unsigned u; } c;
  c.f = f;
  unsigned u = c.u;
  return (u16)((u + 0x7FFFu + ((u >> 16) & 1u)) >> 16);
}

// 64-elem-row bf16 tile helpers: 8-elem groups XOR-swizzled by (row&7),
// 16B aligned accesses, 2-way bank aliasing (free).
__device__ __forceinline__ s16x8 ldfrag(const u16* t, int r, int g) {
  return *(const s16x8*)(t + r * 64 + 8 * (g ^ (r & 7)));
}
__device__ __forceinline__ void stfrag(u16* t, int r, int g, s16x8 v) {
  *(s16x8*)(t + r * 64 + 8 * (g ^ (r & 7))) = v;
}

// ---------------------------------------------------------------- add pos emb
__global__ __launch_bounds__(256) void add_pos_kernel(
    const float* __restrict__ X, const float* __restrict__ P,
    float* __restrict__ Y, int n, int pn) {
  int i = blockIdx.x * 256 + threadIdx.x;
  if (i < n) Y[i] = X[i] + P[i % pn];
}

// ------------------------------------------- weight fp32 -> bf16 + transpose
__global__ __launch_bounds__(256) void wconv_kernel(
    const float* __restrict__ Wq, const float* __restrict__ Wk,
    const float* __restrict__ Wv, const float* __restrict__ Wo,
    const float* __restrict__ W1, const float* __restrict__ W2,
    u16* __restrict__ dst) {
  int mat = blockIdx.z;             // 0..23 = layer*6 + type
  int layer = mat / 6, type = mat % 6;
  const float* srcs[6] = {Wq, Wk, Wv, Wo, W1, W2};
  const float* src = srcs[type] + (size_t)layer * DIM * DIM;
  u16* d = dst + (size_t)mat * DIM * DIM;
  __shared__ float L[32][33];
  int k0 = blockIdx.y * 32, n0 = blockIdx.x * 32;
  int r = threadIdx.x >> 3, c4 = (threadIdx.x & 7) * 4;
  float4 v = *(const float4*)&src[(size_t)(k0 + r) * DIM + n0 + c4];
  L[c4 + 0][r] = v.x; L[c4 + 1][r] = v.y;
  L[c4 + 2][r] = v.z; L[c4 + 3][r] = v.w;
  __syncthreads();
  u16x4 w;
#pragma unroll
  for (int j = 0; j < 4; ++j) w[j] = f2bf(L[r][c4 + j]);
  *(u16x4*)&d[(size_t)(n0 + r) * DIM + k0 + c4] = w;
}

// ----------------------------------------------------- layernorm (bf16 out)
__global__ __launch_bounds__(256) void ln_kernel(
    const float* __restrict__ X, const float* __restrict__ g,
    const float* __restrict__ b, u16* __restrict__ Y) {
  int t = blockIdx.x;
  int tid = threadIdx.x;
  const float* xr = X + (size_t)t * DIM;
  float v0 = xr[tid], v1 = xr[tid + 256], v2 = xr[tid + 512];
  float s = v0 + v1 + v2;
  float q = v0 * v0 + v1 * v1 + v2 * v2;
#pragma unroll
  for (int o = 32; o > 0; o >>= 1) {
    s += __shfl_xor(s, o);
    q += __shfl_xor(q, o);
  }
  __shared__ float rs[4], rq[4];
  int w = tid >> 6;
  if ((tid & 63) == 0) { rs[w] = s; rq[w] = q; }
  __syncthreads();
  s = rs[0] + rs[1] + rs[2] + rs[3];
  q = rq[0] + rq[1] + rq[2] + rq[3];
  float mean = s * (1.0f / DIM);
  float var  = q * (1.0f / DIM) - mean * mean;
  float r = rsqrtf(var + 1e-5f);
  u16* yr = Y + (size_t)t * DIM;
  yr[tid]       = f2bf((v0 - mean) * r * g[tid]       + b[tid]);
  yr[tid + 256] = f2bf((v1 - mean) * r * g[tid + 256] + b[tid + 256]);
  yr[tid + 512] = f2bf((v2 - mean) * r * g[tid + 512] + b[tid + 512]);
}

// ------------------------------------------------------------ bf16 MFMA GEMM
template <int HAS_BIAS, int HAS_GELU, int HAS_RES, int OUT_BF16>
__global__ __launch_bounds__(256, 3) void gemm_bf16(
    const u16* __restrict__ A, const u16* __restrict__ Bt,
    const float* __restrict__ bias, void* __restrict__ Cv) {
  float* C = (float*)Cv;
  u16* Cb = (u16*)Cv;
  __shared__ __align__(16) u16 As[128 * 64];
  __shared__ __align__(16) u16 Bs[128 * 64];
  int tid = threadIdx.x;
  int wave = tid >> 6, lane = tid & 63, ln = lane & 15, quad = lane >> 4;
  int wr = wave >> 1, wc = wave & 1;
  int m0 = blockIdx.y * 128, n0 = blockIdx.x * 128;

  f32x4 acc[4][4];
  const f32x4 zero = {0.0f, 0.0f, 0.0f, 0.0f};
#pragma unroll
  for (int i = 0; i < 4; ++i)
#pragma unroll
    for (int j = 0; j < 4; ++j) acc[i][j] = zero;

  for (int kt = 0; kt < DIM / 64; ++kt) {
#pragma unroll
    for (int i = 0; i < 4; ++i) {
      int s = tid + i * 256;          // 0..1023
      int r = s >> 3, g = s & 7;
      stfrag(As, r, g, *(const s16x8*)&A[(size_t)(m0 + r) * DIM + kt * 64 + g * 8]);
      stfrag(Bs, r, g, *(const s16x8*)&Bt[(size_t)(n0 + r) * DIM + kt * 64 + g * 8]);
    }
    __syncthreads();

    s16x8 bfr0[4], bfr1[4];
#pragma unroll
    for (int ni = 0; ni < 4; ++ni) {
      bfr0[ni] = ldfrag(Bs, wc * 64 + ni * 16 + ln, quad);
      bfr1[ni] = ldfrag(Bs, wc * 64 + ni * 16 + ln, 4 + quad);
    }
#pragma unroll
    for (int mi = 0; mi < 4; ++mi) {
      s16x8 a0 = ldfrag(As, wr * 64 + mi * 16 + ln, quad);
      s16x8 a1 = ldfrag(As, wr * 64 + mi * 16 + ln, 4 + quad);
#pragma unroll
      for (int ni = 0; ni < 4; ++ni) {
        acc[mi][ni] = __builtin_amdgcn_mfma_f32_16x16x32_bf16(a0, bfr0[ni], acc[mi][ni], 0, 0, 0);
        acc[mi][ni] = __builtin_amdgcn_mfma_f32_16x16x32_bf16(a1, bfr1[ni], acc[mi][ni], 0, 0, 0);
      }
    }
    __syncthreads();
  }

#pragma unroll
  for (int ni = 0; ni < 4; ++ni) {
    int c = n0 + wc * 64 + ni * 16 + ln;
    float bv = HAS_BIAS ? bias[c] : 0.0f;
#pragma unroll
    for (int mi = 0; mi < 4; ++mi) {
#pragma unroll
      for (int reg = 0; reg < 4; ++reg) {
        int r = m0 + wr * 64 + mi * 16 + quad * 4 + reg;
        float v = acc[mi][ni][reg] + bv;
        if (HAS_GELU) v = 0.5f * v * (1.0f + erff(v * 0.70710678118654752f));
        size_t o = (size_t)r * DIM + c;
        if (OUT_BF16) { Cb[o] = f2bf(v); }
        else if (HAS_RES) { C[o] += v; }
        else { C[o] = v; }
      }
    }
  }
}

// ------------------------------- V transpose: [T][768] -> [b][h][64][2048]
__global__ __launch_bounds__(256) void vtrans_kernel(
    const u16* __restrict__ Vb, u16* __restrict__ Vt) {
  int bid = blockIdx.x;
  int tt = bid & 31;
  int h  = (bid >> 5) % HEADS;
  int b  = bid / (32 * HEADS);
  int tid = threadIdx.x;
  __shared__ u16 T[64][66];
  const u16* src = Vb + ((size_t)(b * CTXN + tt * 64)) * DIM + h * HD;
#pragma unroll
  for (int i = 0; i < 2; ++i) {
    int idx = tid + i * 256, r = idx >> 3, g = idx & 7;
    s16x8 v = *(const s16x8*)&src[(size_t)r * DIM + g * 8];
#pragma unroll
    for (int j = 0; j < 8; ++j) T[g * 8 + j][r] = (u16)v[j];
  }
  __syncthreads();
#pragma unroll
  for (int i = 0; i < 2; ++i) {
    int idx = tid + i * 256, d = idx >> 3, g = idx & 7;
    s16x8 w;
#pragma unroll
    for (int j = 0; j < 8; ++j) w[j] = (short)T[d][g * 8 + j];
    *(s16x8*)&Vt[((size_t)(b * HEADS + h) * HD + d) * CTXN + tt * 64 + g * 8] = w;
  }
}

// -------------------------------------------------- bf16 MFMA flash attention
// S^T formulation: mfma(Kfrag, Qfrag) gives S^T[k][q] in C-layout so each
// lane owns all scores for one q (col=ln). Softmax state is scalar per lane.
__global__ __launch_bounds__(256) void attn_kernel(
    const u16* __restrict__ Qb, const u16* __restrict__ Kb,
    const u16* __restrict__ Vt, u16* __restrict__ Ob) {
  const int tiles = CTXN / 64;
  int bid = blockIdx.x;
  int qt = bid % tiles;
  int h  = (bid / tiles) % HEADS;
  int b  = bid / (tiles * HEADS);
  int tid = threadIdx.x;
  int wave = tid >> 6, lane = tid & 63, ln = lane & 15, quad = lane >> 4;

  // LDS: Ks 8K | Vs 8K | Ps 8K = 24576 B. Of (64x65 fp32) aliases the pool
  // after the K-loop.
  __shared__ __align__(16) char smem[24576];
  u16* Ks = (u16*)smem;            // K tile  [kc][d]
  u16* Vs = (u16*)(smem + 8192);   // V^T tile [d][kc]
  u16* Ps = (u16*)(smem + 16384);  // P tile  [q][kc]
  float (*Of)[65] = (float (*)[65])smem;

  // loop-invariant Q fragments (B operand: col q = wave*16+ln)
  const u16* qrow =
      Qb + ((size_t)(b * CTXN + qt * 64 + wave * 16 + ln)) * DIM + h * HD;
  s16x8 aq0 = *(const s16x8*)&qrow[quad * 8];
  s16x8 aq1 = *(const s16x8*)&qrow[32 + quad * 8];

  float m = -1e30f, l = 0.0f;
  f32x4 oacc[4];
  const f32x4 zero = {0.0f, 0.0f, 0.0f, 0.0f};
#pragma unroll
  for (int i = 0; i < 4; ++i) oacc[i] = zero;

  const u16* kb0 = Kb + ((size_t)b * CTXN) * DIM + h * HD;
  const u16* vt0 = Vt + ((size_t)(b * HEADS + h) * HD) * CTXN;
  const float lg = 0.125f * 1.4426950408889634f;  // scale * log2(e)

  for (int kt = 0; kt < tiles; ++kt) {
    // stage K tile [kc][d] and V^T tile [d][kc]
#pragma unroll
    for (int i = 0; i < 2; ++i) {
      int idx = tid + i * 256, r = idx >> 3, g = idx & 7;
      stfrag(Ks, r, g, *(const s16x8*)&kb0[(size_t)(kt * 64 + r) * DIM + g * 8]);
      stfrag(Vs, r, g, *(const s16x8*)&vt0[(size_t)r * CTXN + kt * 64 + g * 8]);
    }
    __syncthreads();

    // S^T: per nb (k-block): D[k=nb*16+quad*4+reg][q=wave*16+ln]
    f32x4 sacc[4];
#pragma unroll
    for (int nb = 0; nb < 4; ++nb) {
      sacc[nb] = zero;
      s16x8 k0 = ldfrag(Ks, nb * 16 + ln, quad);
      s16x8 k1 = ldfrag(Ks, nb * 16 + ln, 4 + quad);
      sacc[nb] = __builtin_amdgcn_mfma_f32_16x16x32_bf16(k0, aq0, sacc[nb], 0, 0, 0);
      sacc[nb] = __builtin_amdgcn_mfma_f32_16x16x32_bf16(k1, aq1, sacc[nb], 0, 0, 0);
    }

    // online softmax (exp2 domain), per-lane scalar state for q=wave*16+ln
    float s2[4][4];
    float mx = -1e30f;
#pragma unroll
    for (int nb = 0; nb < 4; ++nb)
#pragma unroll
      for (int reg = 0; reg < 4; ++reg) {
        s2[nb][reg] = sacc[nb][reg] * lg;
        mx = fmaxf(mx, s2[nb][reg]);
      }
    mx = fmaxf(mx, __shfl_xor(mx, 16));
    mx = fmaxf(mx, __shfl_xor(mx, 32));
    float mnew = fmaxf(m, mx);
    float alpha = exp2f(m - mnew);
    float ls = 0.0f;
    u16x4 pk[4];
#pragma unroll
    for (int nb = 0; nb < 4; ++nb)
#pragma unroll
      for (int reg = 0; reg < 4; ++reg) {
        float p = exp2f(s2[nb][reg] - mnew);
        ls += p;
        pk[nb][reg] = f2bf(p);
      }
    ls += __shfl_xor(ls, 16);
    ls += __shfl_xor(ls, 32);
    l = l * alpha + ls;
    m = mnew;

    // write P[q][k]: 4 contiguous u16 per nb (8B), swizzle-consistent
    {
      int row = wave * 16 + ln;
      int rs = row & 7;
      int half = (quad & 1) * 4;
#pragma unroll
      for (int nb = 0; nb < 4; ++nb) {
        int g0 = nb * 2 + (quad >> 1);
        *(u16x4*)&Ps[row * 64 + 8 * (g0 ^ rs) + half] = pk[nb];
      }
    }
    __syncthreads();

    // rescale O accumulators: alpha for q=wave*16+quad*4+reg via shfl
    float ar[4];
#pragma unroll
    for (int reg = 0; reg < 4; ++reg) ar[reg] = __shfl(alpha, quad * 4 + reg);
#pragma unroll
    for (int nb = 0; nb < 4; ++nb)
#pragma unroll
      for (int reg = 0; reg < 4; ++reg) oacc[nb][reg] *= ar[reg];

    // O[q][d] += P x V: A=P rows q (own wave strip), B=V^T rows d
    s16x8 ap0 = ldfrag(Ps, wave * 16 + ln, quad);
    s16x8 ap1 = ldfrag(Ps, wave * 16 + ln, 4 + quad);
#pragma unroll
    for (int nb = 0; nb < 4; ++nb) {
      s16x8 bv0 = ldfrag(Vs, nb * 16 + ln, quad);
      s16x8 bv1 = ldfrag(Vs, nb * 16 + ln, 4 + quad);
      oacc[nb] = __builtin_amdgcn_mfma_f32_16x16x32_bf16(ap0, bv0, oacc[nb], 0, 0, 0);
      oacc[nb] = __builtin_amdgcn_mfma_f32_16x16x32_bf16(ap1, bv1, oacc[nb], 0, 0, 0);
    }
    __syncthreads();
  }

  // normalize: l for q=wave*16+quad*4+reg via shfl
  float li[4];
#pragma unroll
  for (int reg = 0; reg < 4; ++reg) li[reg] = 1.0f / __shfl(l, quad * 4 + reg);

  // O C-layout: row q=wave*16+quad*4+reg, col d=nb*16+ln -> Of[q][d]
#pragma unroll
  for (int nb = 0; nb < 4; ++nb)
#pragma unroll
    for (int reg = 0; reg < 4; ++reg)
      Of[wave * 16 + quad * 4 + reg][nb * 16 + ln] = oacc[nb][reg] * li[reg];
  __syncthreads();
  {
    int r = tid >> 2, c0 = (tid & 3) * 16;
    u16* dst = Ob + ((size_t)(b * CTXN + qt * 64 + r)) * DIM + h * HD + c0;
#pragma unroll
    for (int k = 0; k < 4; ++k) {
      u16x4 w;
#pragma unroll
      for (int j = 0; j < 4; ++j) w[j] = f2bf(Of[r][c0 + 4 * k + j]);
      *(u16x4*)&dst[4 * k] = w;
    }
  }
}

// ------------------------------------------------------------------- launch
extern "C" void kernel_launch(void* const* d_in, const int* in_sizes, int n_in,
                              void* d_out, int out_size, void* d_ws, size_t ws_size,
                              hipStream_t stream) {
  const float* x_in  = (const float*)d_in[0];
  const float* pos   = (const float*)d_in[1];
  const float* ln1_g = (const float*)d_in[2];
  const float* ln1_b = (const float*)d_in[3];
  const float* Wq    = (const float*)d_in[4];
  const float* Wk    = (const float*)d_in[5];
  const float* Wv    = (const float*)d_in[6];
  const float* Wo    = (const float*)d_in[7];
  const float* ln2_g = (const float*)d_in[8];
  const float* ln2_b = (const float*)d_in[9];
  const float* W1    = (const float*)d_in[10];
  const float* b1    = (const float*)d_in[11];
  const float* W2    = (const float*)d_in[12];
  const float* b2    = (const float*)d_in[13];

  float* x = (float*)d_out;
  const size_t TD = (size_t)TOKENS * DIM;
  // ws layout (u16): hb | qb | kb | vb(=fb) | vt | weights(24*768*768)
  u16* hb = (u16*)d_ws;
  u16* qb = hb + TD;
  u16* kb = qb + TD;
  u16* vb = kb + TD;   // aliased as fb for the FFN
  u16* vt = vb + TD;
  u16* wt = vt + TD;
  u16* fb = vb;

  int n = (int)TD, pn = CTXN * DIM;
  add_pos_kernel<<<(n + 255) / 256, 256, 0, stream>>>(x_in, pos, x, n, pn);
  {
    dim3 wg(24, 24, 24);
    wconv_kernel<<<wg, 256, 0, stream>>>(Wq, Wk, Wv, Wo, W1, W2, wt);
  }

  const size_t WSZ = (size_t)DIM * DIM;
  dim3 gg(DIM / 128, TOKENS / 128);  // (6, 64)
  int nblk_attn = BATCH * HEADS * (CTXN / 64);  // 1536
  for (int i = 0; i < DEPTH; ++i) {
    const u16* wq = wt + (size_t)(i * 6 + 0) * WSZ;
    const u16* wk = wt + (size_t)(i * 6 + 1) * WSZ;
    const u16* wv = wt + (size_t)(i * 6 + 2) * WSZ;
    const u16* wo = wt + (size_t)(i * 6 + 3) * WSZ;
    const u16* w1 = wt + (size_t)(i * 6 + 4) * WSZ;
    const u16* w2 = wt + (size_t)(i * 6 + 5) * WSZ;

    // --- attention block ---
    ln_kernel<<<TOKENS, 256, 0, stream>>>(x, ln1_g + i * DIM, ln1_b + i * DIM, hb);
    gemm_bf16<0,0,0,1><<<gg, 256, 0, stream>>>(hb, wq, nullptr, qb);
    gemm_bf16<0,0,0,1><<<gg, 256, 0, stream>>>(hb, wk, nullptr, kb);
    gemm_bf16<0,0,0,1><<<gg, 256, 0, stream>>>(hb, wv, nullptr, vb);
    vtrans_kernel<<<nblk_attn, 256, 0, stream>>>(vb, vt);
    attn_kernel<<<nblk_attn, 256, 0, stream>>>(qb, kb, vt, hb);
    gemm_bf16<0,0,1,0><<<gg, 256, 0, stream>>>(hb, wo, nullptr, x);

    // --- feed-forward block ---
    ln_kernel<<<TOKENS, 256, 0, stream>>>(x, ln2_g + i * DIM, ln2_b + i * DIM, hb);
    gemm_bf16<1,1,0,1><<<gg, 256, 0, stream>>>(hb, w1, b1 + i * DIM, fb);
    gemm_bf16<1,0,1,0><<<gg, 256, 0, stream>>>(fb, w2, b2 + i * DIM, x);
  }
}

// Round 7
// 1252.223 us; speedup vs baseline: 17.2513x; 1.4568x over previous
//
#include <hip/hip_runtime.h>
#include <math.h>

// Transformer: DEPTH=4, DIM=768, HEADS=12, HD=64, CTX=2048, B=4.
// R6: GEMM overhaul — fused QKV GEMM (N=2304, 1152 blocks) + async
// global_load_lds(16B) staging that materializes the XOR-swizzled LDS
// layout directly (lane fetches group (lane&7)^((lane>>3)&7)).
// Attention/LN unchanged from R5.

#define DEPTH 4
#define DIM   768
#define HEADS 12
#define HD    64
#define CTXN  2048
#define BATCH 4
#define TOKENS (BATCH * CTXN)   // 8192
#define QKVS  (3 * DIM)         // 2304

typedef unsigned short u16;
typedef short s16x8 __attribute__((ext_vector_type(8)));   // 8 bf16 (4 VGPRs)
typedef float f32x4 __attribute__((ext_vector_type(4)));   // MFMA acc
typedef u16  u16x4 __attribute__((ext_vector_type(4)));

// float -> bf16 bits, round-nearest-even
__device__ __forceinline__ u16 f2bf(float f) {
  union { float f; unsigned u; } c;
  c.f = f;
  unsigned u = c.u;
  return (u16)((u + 0x7FFFu + ((u >> 16) & 1u)) >> 16);
}

// 64-elem-row bf16 tile helpers: 8-elem groups XOR-swizzled by (row&7).
__device__ __forceinline__ s16x8 ldfrag(const u16* t, int r, int g) {
  return *(const s16x8*)(t + r * 64 + 8 * (g ^ (r & 7)));
}
__device__ __forceinline__ void stfrag(u16* t, int r, int g, s16x8 v) {
  *(s16x8*)(t + r * 64 + 8 * (g ^ (r & 7))) = v;
}

// async 16B/lane global->LDS (lds dest = wave-uniform base + lane*16)
__device__ __forceinline__ void gld_lds16(const u16* g, u16* l) {
#if __has_builtin(__builtin_amdgcn_global_load_lds)
  __builtin_amdgcn_global_load_lds(
      (const __attribute__((address_space(1))) unsigned int*)g,
      (__attribute__((address_space(3))) unsigned int*)l, 16, 0, 0);
#else
  // fallback: manual vector copy (lane scatter identical layout)
  int lane = threadIdx.x & 63;
  *(s16x8*)(l + lane * 8) = *(const s16x8*)(g);
#endif
}

// ---------------------------------------------------------------- add pos emb
__global__ __launch_bounds__(256) void add_pos_kernel(
    const float* __restrict__ X, const float* __restrict__ P,
    float* __restrict__ Y, int n, int pn) {
  int i = blockIdx.x * 256 + threadIdx.x;
  if (i < n) Y[i] = X[i] + P[i % pn];
}

// ------------------------------------------- weight fp32 -> bf16 + transpose
// per layer, mats 0..5 = Wq,Wk,Wv,Wo,W1,W2; q/k/v contiguous => fused [2304][768]
__global__ __launch_bounds__(256) void wconv_kernel(
    const float* __restrict__ Wq, const float* __restrict__ Wk,
    const float* __restrict__ Wv, const float* __restrict__ Wo,
    const float* __restrict__ W1, const float* __restrict__ W2,
    u16* __restrict__ dst) {
  int mat = blockIdx.z;             // 0..23 = layer*6 + type
  int layer = mat / 6, type = mat % 6;
  const float* srcs[6] = {Wq, Wk, Wv, Wo, W1, W2};
  const float* src = srcs[type] + (size_t)layer * DIM * DIM;
  u16* d = dst + (size_t)mat * DIM * DIM;
  __shared__ float L[32][33];
  int k0 = blockIdx.y * 32, n0 = blockIdx.x * 32;
  int r = threadIdx.x >> 3, c4 = (threadIdx.x & 7) * 4;
  float4 v = *(const float4*)&src[(size_t)(k0 + r) * DIM + n0 + c4];
  L[c4 + 0][r] = v.x; L[c4 + 1][r] = v.y;
  L[c4 + 2][r] = v.z; L[c4 + 3][r] = v.w;
  __syncthreads();
  u16x4 w;
#pragma unroll
  for (int j = 0; j < 4; ++j) w[j] = f2bf(L[r][c4 + j]);
  *(u16x4*)&d[(size_t)(n0 + r) * DIM + k0 + c4] = w;
}

// ----------------------------------------------------- layernorm (bf16 out)
__global__ __launch_bounds__(256) void ln_kernel(
    const float* __restrict__ X, const float* __restrict__ g,
    const float* __restrict__ b, u16* __restrict__ Y) {
  int t = blockIdx.x;
  int tid = threadIdx.x;
  const float* xr = X + (size_t)t * DIM;
  float v0 = xr[tid], v1 = xr[tid + 256], v2 = xr[tid + 512];
  float s = v0 + v1 + v2;
  float q = v0 * v0 + v1 * v1 + v2 * v2;
#pragma unroll
  for (int o = 32; o > 0; o >>= 1) {
    s += __shfl_xor(s, o);
    q += __shfl_xor(q, o);
  }
  __shared__ float rs[4], rq[4];
  int w = tid >> 6;
  if ((tid & 63) == 0) { rs[w] = s; rq[w] = q; }
  __syncthreads();
  s = rs[0] + rs[1] + rs[2] + rs[3];
  q = rq[0] + rq[1] + rq[2] + rq[3];
  float mean = s * (1.0f / DIM);
  float var  = q * (1.0f / DIM) - mean * mean;
  float r = rsqrtf(var + 1e-5f);
  u16* yr = Y + (size_t)t * DIM;
  yr[tid]       = f2bf((v0 - mean) * r * g[tid]       + b[tid]);
  yr[tid + 256] = f2bf((v1 - mean) * r * g[tid + 256] + b[tid + 256]);
  yr[tid + 512] = f2bf((v2 - mean) * r * g[tid + 512] + b[tid + 512]);
}

// ------------------------------------------------------------ bf16 MFMA GEMM
// C[M=8192][Nc] = A[M][768] @ Bt[Nc][768]^T. 128x128 tile, BK=64, async
// global_load_lds staging into the swizzled layout.
template <int HAS_BIAS, int HAS_GELU, int HAS_RES, int OUT_BF16>
__global__ __launch_bounds__(256, 3) void gemm_bf16(
    const u16* __restrict__ A, const u16* __restrict__ Bt,
    const float* __restrict__ bias, void* __restrict__ Cv, int Nc) {
  float* C = (float*)Cv;
  u16* Cb = (u16*)Cv;
  __shared__ __align__(16) u16 As[128 * 64];
  __shared__ __align__(16) u16 Bs[128 * 64];
  int tid = threadIdx.x;
  int wave = tid >> 6, lane = tid & 63, ln = lane & 15, quad = lane >> 4;
  int wr = wave >> 1, wc = wave & 1;
  int m0 = blockIdx.y * 128, n0 = blockIdx.x * 128;

  // async staging source: lane fetches the group that lands at lds slot
  // lane*16 under the XOR swizzle: g = (lane&7) ^ ((lane>>3)&7)
  int srow = wave * 32 + (lane >> 3);
  int sg = (lane & 7) ^ ((lane >> 3) & 7);
  const u16* ga = A + (size_t)(m0 + srow) * DIM + sg * 8;
  const u16* gb = Bt + (size_t)(n0 + srow) * DIM + sg * 8;
  u16* la = As + wave * 2048;   // wave-uniform LDS base (32 rows x 64)
  u16* lb = Bs + wave * 2048;

  f32x4 acc[4][4];
  const f32x4 zero = {0.0f, 0.0f, 0.0f, 0.0f};
#pragma unroll
  for (int i = 0; i < 4; ++i)
#pragma unroll
    for (int j = 0; j < 4; ++j) acc[i][j] = zero;

  for (int kt = 0; kt < DIM / 64; ++kt) {
#pragma unroll
    for (int i = 0; i < 4; ++i) {
      gld_lds16(ga + (size_t)i * 8 * DIM, la + i * 512);
      gld_lds16(gb + (size_t)i * 8 * DIM, lb + i * 512);
    }
    ga += 64; gb += 64;
    __syncthreads();

    s16x8 bfr0[4], bfr1[4];
#pragma unroll
    for (int ni = 0; ni < 4; ++ni) {
      bfr0[ni] = ldfrag(Bs, wc * 64 + ni * 16 + ln, quad);
      bfr1[ni] = ldfrag(Bs, wc * 64 + ni * 16 + ln, 4 + quad);
    }
#pragma unroll
    for (int mi = 0; mi < 4; ++mi) {
      s16x8 a0 = ldfrag(As, wr * 64 + mi * 16 + ln, quad);
      s16x8 a1 = ldfrag(As, wr * 64 + mi * 16 + ln, 4 + quad);
#pragma unroll
      for (int ni = 0; ni < 4; ++ni) {
        acc[mi][ni] = __builtin_amdgcn_mfma_f32_16x16x32_bf16(a0, bfr0[ni], acc[mi][ni], 0, 0, 0);
        acc[mi][ni] = __builtin_amdgcn_mfma_f32_16x16x32_bf16(a1, bfr1[ni], acc[mi][ni], 0, 0, 0);
      }
    }
    __syncthreads();
  }

#pragma unroll
  for (int ni = 0; ni < 4; ++ni) {
    int c = n0 + wc * 64 + ni * 16 + ln;
    float bv = HAS_BIAS ? bias[c] : 0.0f;
#pragma unroll
    for (int mi = 0; mi < 4; ++mi) {
#pragma unroll
      for (int reg = 0; reg < 4; ++reg) {
        int r = m0 + wr * 64 + mi * 16 + quad * 4 + reg;
        float v = acc[mi][ni][reg] + bv;
        if (HAS_GELU) v = 0.5f * v * (1.0f + erff(v * 0.70710678118654752f));
        size_t o = (size_t)r * Nc + c;
        if (OUT_BF16) { Cb[o] = f2bf(v); }
        else if (HAS_RES) { C[o] += v; }
        else { C[o] = v; }
      }
    }
  }
}

// ---------------- V transpose: qkv[T][2304] (V part) -> [b][h][64][2048]
__global__ __launch_bounds__(256) void vtrans_kernel(
    const u16* __restrict__ QKV, u16* __restrict__ Vt) {
  int bid = blockIdx.x;
  int tt = bid & 31;
  int h  = (bid >> 5) % HEADS;
  int b  = bid / (32 * HEADS);
  int tid = threadIdx.x;
  __shared__ u16 T[64][66];
  const u16* src = QKV + ((size_t)(b * CTXN + tt * 64)) * QKVS + 2 * DIM + h * HD;
#pragma unroll
  for (int i = 0; i < 2; ++i) {
    int idx = tid + i * 256, r = idx >> 3, g = idx & 7;
    s16x8 v = *(const s16x8*)&src[(size_t)r * QKVS + g * 8];
#pragma unroll
    for (int j = 0; j < 8; ++j) T[g * 8 + j][r] = (u16)v[j];
  }
  __syncthreads();
#pragma unroll
  for (int i = 0; i < 2; ++i) {
    int idx = tid + i * 256, d = idx >> 3, g = idx & 7;
    s16x8 w;
#pragma unroll
    for (int j = 0; j < 8; ++j) w[j] = (short)T[d][g * 8 + j];
    *(s16x8*)&Vt[((size_t)(b * HEADS + h) * HD + d) * CTXN + tt * 64 + g * 8] = w;
  }
}

// -------------------------------------------------- bf16 MFMA flash attention
// S^T formulation (R5), Q/K read from fused qkv buffer (stride 2304).
__global__ __launch_bounds__(256) void attn_kernel(
    const u16* __restrict__ QKV, const u16* __restrict__ Vt,
    u16* __restrict__ Ob) {
  const int tiles = CTXN / 64;
  int bid = blockIdx.x;
  int qt = bid % tiles;
  int h  = (bid / tiles) % HEADS;
  int b  = bid / (tiles * HEADS);
  int tid = threadIdx.x;
  int wave = tid >> 6, lane = tid & 63, ln = lane & 15, quad = lane >> 4;

  __shared__ __align__(16) char smem[24576];
  u16* Ks = (u16*)smem;            // K tile  [kc][d]
  u16* Vs = (u16*)(smem + 8192);   // V^T tile [d][kc]
  u16* Ps = (u16*)(smem + 16384);  // P tile  [q][kc]
  float (*Of)[65] = (float (*)[65])smem;

  const u16* qrow =
      QKV + ((size_t)(b * CTXN + qt * 64 + wave * 16 + ln)) * QKVS + h * HD;
  s16x8 aq0 = *(const s16x8*)&qrow[quad * 8];
  s16x8 aq1 = *(const s16x8*)&qrow[32 + quad * 8];

  float m = -1e30f, l = 0.0f;
  f32x4 oacc[4];
  const f32x4 zero = {0.0f, 0.0f, 0.0f, 0.0f};
#pragma unroll
  for (int i = 0; i < 4; ++i) oacc[i] = zero;

  const u16* kb0 = QKV + ((size_t)b * CTXN) * QKVS + DIM + h * HD;
  const u16* vt0 = Vt + ((size_t)(b * HEADS + h) * HD) * CTXN;
  const float lg = 0.125f * 1.4426950408889634f;  // scale * log2(e)

  for (int kt = 0; kt < tiles; ++kt) {
#pragma unroll
    for (int i = 0; i < 2; ++i) {
      int idx = tid + i * 256, r = idx >> 3, g = idx & 7;
      stfrag(Ks, r, g, *(const s16x8*)&kb0[(size_t)(kt * 64 + r) * QKVS + g * 8]);
      stfrag(Vs, r, g, *(const s16x8*)&vt0[(size_t)r * CTXN + kt * 64 + g * 8]);
    }
    __syncthreads();

    f32x4 sacc[4];
#pragma unroll
    for (int nb = 0; nb < 4; ++nb) {
      sacc[nb] = zero;
      s16x8 k0 = ldfrag(Ks, nb * 16 + ln, quad);
      s16x8 k1 = ldfrag(Ks, nb * 16 + ln, 4 + quad);
      sacc[nb] = __builtin_amdgcn_mfma_f32_16x16x32_bf16(k0, aq0, sacc[nb], 0, 0, 0);
      sacc[nb] = __builtin_amdgcn_mfma_f32_16x16x32_bf16(k1, aq1, sacc[nb], 0, 0, 0);
    }

    float s2[4][4];
    float mx = -1e30f;
#pragma unroll
    for (int nb = 0; nb < 4; ++nb)
#pragma unroll
      for (int reg = 0; reg < 4; ++reg) {
        s2[nb][reg] = sacc[nb][reg] * lg;
        mx = fmaxf(mx, s2[nb][reg]);
      }
    mx = fmaxf(mx, __shfl_xor(mx, 16));
    mx = fmaxf(mx, __shfl_xor(mx, 32));
    float mnew = fmaxf(m, mx);
    float alpha = exp2f(m - mnew);
    float ls = 0.0f;
    u16x4 pk[4];
#pragma unroll
    for (int nb = 0; nb < 4; ++nb)
#pragma unroll
      for (int reg = 0; reg < 4; ++reg) {
        float p = exp2f(s2[nb][reg] - mnew);
        ls += p;
        pk[nb][reg] = f2bf(p);
      }
    ls += __shfl_xor(ls, 16);
    ls += __shfl_xor(ls, 32);
    l = l * alpha + ls;
    m = mnew;

    {
      int row = wave * 16 + ln;
      int rs = row & 7;
      int half = (quad & 1) * 4;
#pragma unroll
      for (int nb = 0; nb < 4; ++nb) {
        int g0 = nb * 2 + (quad >> 1);
        *(u16x4*)&Ps[row * 64 + 8 * (g0 ^ rs) + half] = pk[nb];
      }
    }
    __syncthreads();

    float ar[4];
#pragma unroll
    for (int reg = 0; reg < 4; ++reg) ar[reg] = __shfl(alpha, quad * 4 + reg);
#pragma unroll
    for (int nb = 0; nb < 4; ++nb)
#pragma unroll
      for (int reg = 0; reg < 4; ++reg) oacc[nb][reg] *= ar[reg];

    s16x8 ap0 = ldfrag(Ps, wave * 16 + ln, quad);
    s16x8 ap1 = ldfrag(Ps, wave * 16 + ln, 4 + quad);
#pragma unroll
    for (int nb = 0; nb < 4; ++nb) {
      s16x8 bv0 = ldfrag(Vs, nb * 16 + ln, quad);
      s16x8 bv1 = ldfrag(Vs, nb * 16 + ln, 4 + quad);
      oacc[nb] = __builtin_amdgcn_mfma_f32_16x16x32_bf16(ap0, bv0, oacc[nb], 0, 0, 0);
      oacc[nb] = __builtin_amdgcn_mfma_f32_16x16x32_bf16(ap1, bv1, oacc[nb], 0, 0, 0);
    }
    __syncthreads();
  }

  float li[4];
#pragma unroll
  for (int reg = 0; reg < 4; ++reg) li[reg] = 1.0f / __shfl(l, quad * 4 + reg);

#pragma unroll
  for (int nb = 0; nb < 4; ++nb)
#pragma unroll
    for (int reg = 0; reg < 4; ++reg)
      Of[wave * 16 + quad * 4 + reg][nb * 16 + ln] = oacc[nb][reg] * li[reg];
  __syncthreads();
  {
    int r = tid >> 2, c0 = (tid & 3) * 16;
    u16* dst = Ob + ((size_t)(b * CTXN + qt * 64 + r)) * DIM + h * HD + c0;
#pragma unroll
    for (int k = 0; k < 4; ++k) {
      u16x4 w;
#pragma unroll
      for (int j = 0; j < 4; ++j) w[j] = f2bf(Of[r][c0 + 4 * k + j]);
      *(u16x4*)&dst[4 * k] = w;
    }
  }
}

// ------------------------------------------------------------------- launch
extern "C" void kernel_launch(void* const* d_in, const int* in_sizes, int n_in,
                              void* d_out, int out_size, void* d_ws, size_t ws_size,
                              hipStream_t stream) {
  const float* x_in  = (const float*)d_in[0];
  const float* pos   = (const float*)d_in[1];
  const float* ln1_g = (const float*)d_in[2];
  const float* ln1_b = (const float*)d_in[3];
  const float* Wq    = (const float*)d_in[4];
  const float* Wk    = (const float*)d_in[5];
  const float* Wv    = (const float*)d_in[6];
  const float* Wo    = (const float*)d_in[7];
  const float* ln2_g = (const float*)d_in[8];
  const float* ln2_b = (const float*)d_in[9];
  const float* W1    = (const float*)d_in[10];
  const float* b1    = (const float*)d_in[11];
  const float* W2    = (const float*)d_in[12];
  const float* b2    = (const float*)d_in[13];

  float* x = (float*)d_out;
  const size_t TD = (size_t)TOKENS * DIM;
  // ws layout (u16): hb(TD) | qkv(3TD) | vt(TD) | wt(24*WSZ); fb aliases qkv
  u16* hb  = (u16*)d_ws;
  u16* qkv = hb + TD;
  u16* vt  = qkv + 3 * TD;
  u16* wt  = vt + TD;
  u16* fb  = qkv;

  int n = (int)TD, pn = CTXN * DIM;
  add_pos_kernel<<<(n + 255) / 256, 256, 0, stream>>>(x_in, pos, x, n, pn);
  {
    dim3 wg(24, 24, 24);
    wconv_kernel<<<wg, 256, 0, stream>>>(Wq, Wk, Wv, Wo, W1, W2, wt);
  }

  const size_t WSZ = (size_t)DIM * DIM;
  dim3 gq(QKVS / 128, TOKENS / 128);  // (18, 64) fused QKV
  dim3 gg(DIM / 128, TOKENS / 128);   // (6, 64)
  int nblk_attn = BATCH * HEADS * (CTXN / 64);  // 1536
  for (int i = 0; i < DEPTH; ++i) {
    const u16* wqkv = wt + (size_t)(i * 6 + 0) * WSZ;  // [2304][768]
    const u16* wo   = wt + (size_t)(i * 6 + 3) * WSZ;
    const u16* w1   = wt + (size_t)(i * 6 + 4) * WSZ;
    const u16* w2   = wt + (size_t)(i * 6 + 5) * WSZ;

    // --- attention block ---
    ln_kernel<<<TOKENS, 256, 0, stream>>>(x, ln1_g + i * DIM, ln1_b + i * DIM, hb);
    gemm_bf16<0,0,0,1><<<gq, 256, 0, stream>>>(hb, wqkv, nullptr, qkv, QKVS);
    vtrans_kernel<<<nblk_attn, 256, 0, stream>>>(qkv, vt);
    attn_kernel<<<nblk_attn, 256, 0, stream>>>(qkv, vt, hb);
    gemm_bf16<0,0,1,0><<<gg, 256, 0, stream>>>(hb, wo, nullptr, x, DIM);

    // --- feed-forward block ---
    ln_kernel<<<TOKENS, 256, 0, stream>>>(x, ln2_g + i * DIM, ln2_b + i * DIM, hb);
    gemm_bf16<1,1,0,1><<<gg, 256, 0, stream>>>(hb, w1, b1 + i * DIM, fb, DIM);
    gemm_bf16<1,0,1,0><<<gg, 256, 0, stream>>>(fb, w2, b2 + i * DIM, x, DIM);
  }
}